// Round 5
// baseline (517.469 us; speedup 1.0000x reference)
//
#include <hip/hip_runtime.h>
#include <hip/hip_bf16.h>

#define D   128
#define DM  256
#define DI  512
#define HH  512
#define KNN 10
#define NN  64
#define BQ  4096
#define BS  128
#define BM2 (BQ + BS)        // 4224 batched se rows
#define G4  2048             // 4*HH
#define GN  2048             // LSTM GEMM N
#define GK  256              // LSTM GEMM K
#define NSYM 200000

__device__ __forceinline__ float sigmoidf_(float x) {
    return 1.f / (1.f + __expf(-x));
}
__device__ __forceinline__ float tanh_fast(float x) {
    x = fminf(fmaxf(x, -20.f), 20.f);
    float e = __expf(2.f * x);
    return (e - 1.f) / (e + 1.f);
}
__device__ __forceinline__ ushort f2bf(float x) {
    union { float f; unsigned u; } v; v.f = x;
    unsigned r = (v.u + 0x7fffu + ((v.u >> 16) & 1u)) >> 16;  // RNE
    return (ushort)r;
}

typedef __bf16  bf16x8  __attribute__((ext_vector_type(8)));
typedef float   floatx4 __attribute__((ext_vector_type(4)));

// ---------------- embedding row norms (once) ----------------
__global__ __launch_bounds__(256) void norms_kernel(
    const float* __restrict__ emb, float* __restrict__ norms)
{
    int wave = threadIdx.x >> 6, lane = threadIdx.x & 63;
    int row = blockIdx.x * 4 + wave;
    if (row >= NSYM) return;
    float2 v = *(const float2*)&emb[(size_t)row * D + lane * 2];
    float s = v.x * v.x + v.y * v.y;
    #pragma unroll
    for (int off = 32; off; off >>= 1) s += __shfl_xor(s, off);
    if (lane == 0) norms[row] = sqrtf(s);
}

// ---------------- neighbor encoder: register fragments + norm table ----------------
__global__ __launch_bounds__(256) void ne_kernel(
    const int* __restrict__ conn_l, const int* __restrict__ conn_r,
    const int* __restrict__ ids, const float* __restrict__ emb,
    const float* __restrict__ norms, float* __restrict__ catm_out)
{
    int row = blockIdx.x >> 1;
    int side = blockIdx.x & 1;
    const int* conn = (side ? conn_r : conn_l) + (size_t)row * NN * 2;
    int cid = ids[row * 2 + side];

    __shared__ int   connb[NN * 2];   // [2j]=rel, [2j+1]=ent
    __shared__ float sim[NN];
    __shared__ int   selr[KNN], sele[KNN];

    int tid = threadIdx.x;
    int wave = tid >> 6, lane = tid & 63;

    if (tid < NN * 2) connb[tid] = conn[tid];
    float2 c01 = *(const float2*)&emb[(size_t)cid * D + lane * 2];
    float c0 = c01.x, c1 = c01.y;
    float cnorm = fmaxf(norms[cid], 1e-8f);
    __syncthreads();

    int cj[16];
    #pragma unroll
    for (int t = 0; t < 16; t++) cj[t] = connb[(wave * 16 + t) * 2 + 1];
    float2 ef[16];
    #pragma unroll
    for (int t = 0; t < 16; t++)
        ef[t] = *(const float2*)&emb[(size_t)cj[t] * D + lane * 2];

    // dot-only ladder (norms come from the table)
    #pragma unroll
    for (int t = 0; t < 16; t++) {
        float dot = c0 * ef[t].x + c1 * ef[t].y;
        #pragma unroll
        for (int off = 32; off; off >>= 1) dot += __shfl_xor(dot, off);
        if (lane == 0) sim[wave * 16 + t] = dot / cnorm;
    }
    __syncthreads();
    if (tid < NN) sim[tid] = sim[tid] / fmaxf(norms[connb[tid * 2 + 1]], 1e-8f);
    __syncthreads();

    // top-10 by (max value, min index) — matches jax.lax.top_k tie-breaking
    // (duplicate ent ids give bit-identical sims: same ladder + same table norm)
    if (wave == 0) {
        float s = sim[lane];
        int id = lane;
        for (int k = 0; k < KNN; k++) {
            float bs = s; int bi = id;
            #pragma unroll
            for (int off = 32; off; off >>= 1) {
                float os = __shfl_xor(bs, off);
                int   oi = __shfl_xor(bi, off);
                if (os > bs || (os == bs && oi < bi)) { bs = os; bi = oi; }
            }
            if (lane == 0) { selr[k] = connb[bi * 2]; sele[k] = connb[bi * 2 + 1]; }
            if (id == bi) s = -__builtin_inff();
        }
    }
    __syncthreads();

    float acc = 0.f;
    if (tid < D) {
        #pragma unroll
        for (int k = 0; k < KNN; k++) acc += emb[(size_t)selr[k] * D + tid];
    } else {
        int d = tid - D;
        #pragma unroll
        for (int k = 0; k < KNN; k++) acc += emb[(size_t)sele[k] * D + d];
    }
    catm_out[(size_t)blockIdx.x * DM + tid] = acc * (1.f / KNN);
}

// ---------------- batched GCN transform ----------------
#define GR 16
__global__ __launch_bounds__(256) void gcn_kernel(
    const float* __restrict__ catm, const float* __restrict__ gcn_W,
    const float* __restrict__ gcn_wb, const float* __restrict__ gcn_b,
    float* __restrict__ out, ushort* __restrict__ out_bf)
{
    __shared__ float cs[GR][DM];
    __shared__ float pp[GR][DM];
    int tid = threadIdx.x;
    int m0 = blockIdx.x * GR;
    #pragma unroll
    for (int t = 0; t < 4; t++) {
        int chunk = tid + 256 * t;
        int r = chunk >> 6, c4 = chunk & 63;
        *(float4*)&cs[r][c4 * 4] = *(const float4*)&catm[(size_t)(m0 + r) * DM + c4 * 4];
    }
    __syncthreads();

    int d = tid & 127, half = tid >> 7;
    float a[GR];
    #pragma unroll
    for (int r = 0; r < GR; r++) a[r] = 0.f;
    const float4* W4 = (const float4*)(gcn_W + (size_t)d * DM + half * D);
    for (int f4 = 0; f4 < D / 4; ++f4) {
        float4 w = W4[f4];
        #pragma unroll
        for (int r = 0; r < GR; r++) {
            const float* c = &cs[r][half * D + f4 * 4];
            a[r] += w.x * c[0] + w.y * c[1] + w.z * c[2] + w.w * c[3];
        }
    }
    #pragma unroll
    for (int r = 0; r < GR; r++) pp[r][tid] = a[r];
    __syncthreads();
    if (tid < D) {
        #pragma unroll
        for (int r = 0; r < GR; r++) {
            float h = pp[r][tid] + pp[r][tid + D] + gcn_wb[tid] + gcn_b[tid];
            float th = tanh_fast(h);
            out[(size_t)(m0 + r) * D + tid] = th;
            out_bf[(size_t)(m0 + r) * D + tid] = f2bf(th);
        }
    }
}

// ---------------- weight conversion: gate-interleaved permutation ----------------
// permuted row n: bn=n>>7, r=n&127, half=(r>>6)&1, j=(r>>4)&3, l=r&15
//   -> unit u = bn*32 + half*16 + l, old row = j*512 + u
__global__ __launch_bounds__(256) void wcvt_kernel(
    const float* __restrict__ W_ih, const float* __restrict__ W_hh,
    const float* __restrict__ se_w1, const float* __restrict__ se_w2,
    ushort* __restrict__ wih_bf, ushort* __restrict__ whh_bf,
    ushort* __restrict__ w1_bf, ushort* __restrict__ w2_bf)
{
    int idx = blockIdx.x * 256 + threadIdx.x;   // 0 .. 2048*256-1
    int n = idx >> 8, k = idx & 255;
    int bn = n >> 7, r = n & 127;
    int half = (r >> 6) & 1, j = (r >> 4) & 3, l = r & 15;
    int u = bn * 32 + half * 16 + l;
    int oldrow = j * 512 + u;
    wih_bf[idx] = f2bf(W_ih[(size_t)oldrow * DM + k]);
    whh_bf[idx] = f2bf(W_hh[(size_t)oldrow * HH + k]);
    if (idx < DI * DM) {
        w1_bf[idx] = f2bf(se_w1[idx]);
        w2_bf[idx] = f2bf(se_w2[idx]);
    }
}

// ---------------- bf16 MFMA GEMM tile params ----------------
#define BMT 128
#define BNT 128
#define BKT 64
#define LDP (BKT + 8)

#define GEMM_CORE(AP, BP, KDIM)                                               \
    floatx4 acc[4][4];                                                        \
    _Pragma("unroll")                                                         \
    for (int i = 0; i < 4; i++)                                               \
        _Pragma("unroll")                                                     \
        for (int j = 0; j < 4; j++) acc[i][j] = (floatx4){0.f, 0.f, 0.f, 0.f};\
    for (int k0 = 0; k0 < (KDIM); k0 += BKT) {                                \
        __syncthreads();                                                      \
        _Pragma("unroll")                                                     \
        for (int t = 0; t < 4; t++) {                                         \
            int chunk = tid + 256 * t;                                        \
            int r = chunk >> 3;                                               \
            int c8 = (chunk & 7) * 8;                                         \
            *(uint4*)&As[r][c8] = *(const uint4*)&(AP)[(size_t)(bm * BMT + r) * (KDIM) + k0 + c8]; \
            *(uint4*)&Bs[r][c8] = *(const uint4*)&(BP)[(size_t)(bn * BNT + r) * (KDIM) + k0 + c8]; \
        }                                                                     \
        __syncthreads();                                                      \
        _Pragma("unroll")                                                     \
        for (int kk = 0; kk < BKT; kk += 32) {                                \
            bf16x8 af[4], bf[4];                                              \
            _Pragma("unroll")                                                 \
            for (int i = 0; i < 4; i++)                                       \
                af[i] = *(const bf16x8*)&As[wm + i * 16 + l16][kk + quad * 8];\
            _Pragma("unroll")                                                 \
            for (int j = 0; j < 4; j++)                                       \
                bf[j] = *(const bf16x8*)&Bs[wn + j * 16 + l16][kk + quad * 8];\
            _Pragma("unroll")                                                 \
            for (int i = 0; i < 4; i++)                                       \
                _Pragma("unroll")                                             \
                for (int j = 0; j < 4; j++)                                   \
                    acc[i][j] = __builtin_amdgcn_mfma_f32_16x16x32_bf16(      \
                        af[i], bf[j], acc[i][j], 0, 0, 0);                    \
        }                                                                     \
    }

#define GEMM_PRE()                                                            \
    __shared__ __align__(16) ushort As[BMT][LDP];                             \
    __shared__ __align__(16) ushort Bs[BNT][LDP];                             \
    int tid = threadIdx.x;                                                    \
    int wave = tid >> 6, lane = tid & 63;                                     \
    int quad = lane >> 4, l16 = lane & 15;                                    \
    int bm = blockIdx.x, bn = blockIdx.y;                                     \
    int wm = (wave >> 1) * 64, wn = (wave & 1) * 64;                          \
    (void)wave;

// se GEMM1: t1 = relu(x @ w1^T + b1), bf16 out
__global__ __launch_bounds__(256) void se_gemm1_kernel(
    const ushort* __restrict__ A, const ushort* __restrict__ B,
    const float* __restrict__ b1, ushort* __restrict__ Cbf)
{
    GEMM_PRE();
    GEMM_CORE(A, B, DM);
    #pragma unroll
    for (int i = 0; i < 4; i++) {
        #pragma unroll
        for (int j = 0; j < 4; j++) {
            int row = bm * BMT + wm + i * 16 + quad * 4;
            int col = bn * BNT + wn + j * 16 + l16;
            float bb = b1[col];
            #pragma unroll
            for (int rr = 0; rr < 4; rr++)
                Cbf[(size_t)(row + rr) * DI + col] = f2bf(fmaxf(acc[i][j][rr] + bb, 0.f));
        }
    }
}

// se GEMM2: y = t1 @ w2^T + b2 + x, fp32 out
__global__ __launch_bounds__(256) void se_gemm2_kernel(
    const ushort* __restrict__ A, const ushort* __restrict__ B,
    const float* __restrict__ b2, const float* __restrict__ xres,
    float* __restrict__ C)
{
    GEMM_PRE();
    GEMM_CORE(A, B, DI);
    #pragma unroll
    for (int i = 0; i < 4; i++) {
        #pragma unroll
        for (int j = 0; j < 4; j++) {
            int row = bm * BMT + wm + i * 16 + quad * 4;
            int col = bn * BNT + wn + j * 16 + l16;
            float bb = b2[col];
            #pragma unroll
            for (int rr = 0; rr < 4; rr++)
                C[(size_t)(row + rr) * DM + col] =
                    acc[i][j][rr] + bb + xres[(size_t)(row + rr) * DM + col];
        }
    }
}

// ---------------- LayerNorm ----------------
#define LN_ROWS 8
__global__ __launch_bounds__(256) void ln_kernel(
    const float* __restrict__ ys, const float* __restrict__ g,
    const float* __restrict__ b, float* __restrict__ outf,
    ushort* __restrict__ outbf)
{
    int tid = threadIdx.x;
    int wave = tid >> 6, lane = tid & 63;
    int r0 = blockIdx.x * LN_ROWS;
    for (int rr = 0; rr < 2; ++rr) {
        int r = r0 + wave * 2 + rr;
        float vals[4];
        float s = 0.f;
        #pragma unroll
        for (int e = 0; e < 4; e++) {
            vals[e] = ys[(size_t)r * DM + e * 64 + lane];
            s += vals[e];
        }
        #pragma unroll
        for (int off = 32; off; off >>= 1) s += __shfl_xor(s, off);
        float mu = s * (1.f / DM);
        float v = 0.f;
        #pragma unroll
        for (int e = 0; e < 4; e++) { float dd = vals[e] - mu; v += dd * dd; }
        #pragma unroll
        for (int off = 32; off; off >>= 1) v += __shfl_xor(v, off);
        float rstd = rsqrtf(v * (1.f / DM) + 1e-5f);
        #pragma unroll
        for (int e = 0; e < 4; e++) {
            int dd = e * 64 + lane;
            float ov = (vals[e] - mu) * rstd * g[dd] + b[dd];
            outf[(size_t)r * DM + dd] = ov;
            outbf[(size_t)r * DM + dd] = f2bf(ov);
        }
    }
}

// ------- sg mean + per-gate constants (permuted layout) -------
__global__ __launch_bounds__(256) void sgw_kernel(
    const float* __restrict__ ln_f, const float* __restrict__ W_hh,
    const float* __restrict__ b_ih, const float* __restrict__ b_hh,
    float* __restrict__ sg, float* __restrict__ bsumP, float* __restrict__ gaddP)
{
    __shared__ float s[DM];
    int tid = threadIdx.x;
    float a = 0.f;
    for (int r = 0; r < BS; r++) a += ln_f[(size_t)(BQ + r) * DM + tid];
    a *= (1.f / BS);
    s[tid] = a;
    if (blockIdx.x == 0) sg[tid] = a;
    __syncthreads();

    int grow = blockIdx.x * 256 + tid;     // old gate row 0..2047
    const float4* w4 = (const float4*)(W_hh + (size_t)grow * HH + DM);
    float acc = 0.f;
    for (int f4 = 0; f4 < DM / 4; ++f4) {
        float4 w = w4[f4];
        acc += w.x * s[f4 * 4] + w.y * s[f4 * 4 + 1] + w.z * s[f4 * 4 + 2] + w.w * s[f4 * 4 + 3];
    }
    float bs = b_ih[grow] + b_hh[grow];
    int g = grow >> 9, u = grow & 511;
    int n = (u >> 5) * 128 + ((u >> 4) & 1) * 64 + g * 16 + (u & 15);
    bsumP[n] = bs;
    gaddP[n] = bs + acc;
}

// ---------------- LSTM GEMM step 1 (fused ew1): A=ln_bf, B=wih_perm ----------------
// Writes P0 fragment-major, c fragment-major, h_bf (units<256).
__global__ __launch_bounds__(256) void lstm_gemm0_kernel(
    const ushort* __restrict__ A, const ushort* __restrict__ B,
    const float* __restrict__ bsumP, const float* __restrict__ lnf,
    float* __restrict__ P0f, float* __restrict__ Cf, ushort* __restrict__ h_out)
{
    GEMM_PRE();
    GEMM_CORE(A, B, GK);
    int u = bn * 32 + (wn ? 16 : 0) + l16;
    float b4[4];
    #pragma unroll
    for (int j = 0; j < 4; j++) b4[j] = bsumP[bn * 128 + wn + j * 16 + l16];
    float* p0lane = P0f + (((size_t)(bm * 16 + bn) * 256 + tid) * 64);
    float* clane  = Cf  + (((size_t)(bm * 16 + bn) * 256 + tid) * 16);
    #pragma unroll
    for (int i = 0; i < 4; i++) {
        int row = bm * BMT + wm + i * 16 + quad * 4;
        #pragma unroll
        for (int rr = 0; rr < 4; rr++) {
            float gi_ = acc[i][0][rr], gf_ = acc[i][1][rr];
            float gg_ = acc[i][2][rr], go_ = acc[i][3][rr];
            p0lane[i * 16 + 0 * 4 + rr] = gi_;
            p0lane[i * 16 + 1 * 4 + rr] = gf_;
            p0lane[i * 16 + 2 * 4 + rr] = gg_;
            p0lane[i * 16 + 3 * 4 + rr] = go_;
            float iv = gi_ + b4[0], gv = gg_ + b4[2], ov = go_ + b4[3];
            float cv = sigmoidf_(iv) * tanh_fast(gv);
            clane[i * 4 + rr] = cv;
            if (bn < 8) {
                float h = lnf[(size_t)(row + rr) * DM + u] + sigmoidf_(ov) * tanh_fast(cv);
                h_out[(size_t)(row + rr) * DM + u] = f2bf(h);
            }
        }
    }
}

// ---------------- LSTM GEMM steps 2..4 (fused ew): A=h_bf(prev), B=whh_perm ----------------
__global__ __launch_bounds__(256) void lstm_step_kernel(
    const ushort* __restrict__ A, const ushort* __restrict__ B,
    const float* __restrict__ P0f, const float* __restrict__ gaddP,
    const float* __restrict__ lnf, float* __restrict__ Cf,
    ushort* __restrict__ h_out, float* __restrict__ hf_out, int last)
{
    GEMM_PRE();
    GEMM_CORE(A, B, GK);
    int u = bn * 32 + (wn ? 16 : 0) + l16;
    float g4[4];
    #pragma unroll
    for (int j = 0; j < 4; j++) g4[j] = gaddP[bn * 128 + wn + j * 16 + l16];
    const float4* p0lane = (const float4*)(P0f + (((size_t)(bm * 16 + bn) * 256 + tid) * 64));
    float* clane = Cf + (((size_t)(bm * 16 + bn) * 256 + tid) * 16);
    #pragma unroll
    for (int i = 0; i < 4; i++) {
        int row = bm * BMT + wm + i * 16 + quad * 4;
        float4 p0i = p0lane[i * 4 + 0];
        float4 p0f_ = p0lane[i * 4 + 1];
        float4 p0g = p0lane[i * 4 + 2];
        float4 p0o = p0lane[i * 4 + 3];
        #pragma unroll
        for (int rr = 0; rr < 4; rr++) {
            float iv = acc[i][0][rr] + ((const float*)&p0i)[rr] + g4[0];
            float fv = acc[i][1][rr] + ((const float*)&p0f_)[rr] + g4[1];
            float gv = acc[i][2][rr] + ((const float*)&p0g)[rr] + g4[2];
            float ov = acc[i][3][rr] + ((const float*)&p0o)[rr] + g4[3];
            float cv = sigmoidf_(fv) * clane[i * 4 + rr] + sigmoidf_(iv) * tanh_fast(gv);
            clane[i * 4 + rr] = cv;
            if (bn < 8) {
                float h = lnf[(size_t)(row + rr) * DM + u] + sigmoidf_(ov) * tanh_fast(cv);
                if (last) hf_out[(size_t)(row + rr) * DM + u] = h;
                else      h_out[(size_t)(row + rr) * DM + u] = f2bf(h);
            }
        }
    }
}

// ---------------- final cosine ----------------
__global__ __launch_bounds__(256) void final_kernel(
    const float* __restrict__ h_ws, const float* __restrict__ sg,
    float* __restrict__ outp)
{
    __shared__ float sgs[DM];
    int tid = threadIdx.x;
    sgs[tid] = sg[tid];
    __syncthreads();
    int wave = tid >> 6, lane = tid & 63;
    float sn = 0.f;
    #pragma unroll
    for (int e = 0; e < 4; e++) { float v = sgs[e * 64 + lane]; sn += v * v; }
    #pragma unroll
    for (int off = 32; off; off >>= 1) sn += __shfl_xor(sn, off);
    float sgnorm = fmaxf(sqrtf(sn), 1e-12f);

    int row = blockIdx.x * 4 + wave;
    const float* h = h_ws + (size_t)row * DM;
    float dot = 0.f, hn = 0.f;
    #pragma unroll
    for (int e = 0; e < 4; e++) {
        float hv = h[e * 64 + lane];
        dot += hv * sgs[e * 64 + lane];
        hn += hv * hv;
    }
    #pragma unroll
    for (int off = 32; off; off >>= 1) { dot += __shfl_xor(dot, off); hn += __shfl_xor(hn, off); }
    if (lane == 0) outp[row] = dot / (fmaxf(sqrtf(hn), 1e-12f) * sgnorm);
}

extern "C" void kernel_launch(void* const* d_in, const int* in_sizes, int n_in,
                              void* d_out, int out_size, void* d_ws, size_t ws_size,
                              hipStream_t stream)
{
    const int* query    = (const int*)d_in[0];
    const int* support  = (const int*)d_in[1];
    const int* q_l_conn = (const int*)d_in[2];
    const int* q_r_conn = (const int*)d_in[4];
    const int* s_l_conn = (const int*)d_in[6];
    const int* s_r_conn = (const int*)d_in[8];
    const float* emb    = (const float*)d_in[10];
    const float* gcn_W  = (const float*)d_in[11];
    const float* gcn_wb = (const float*)d_in[12];
    const float* gcn_b  = (const float*)d_in[13];
    const float* se_w1  = (const float*)d_in[14];
    const float* se_b1  = (const float*)d_in[15];
    const float* se_w2  = (const float*)d_in[16];
    const float* se_b2  = (const float*)d_in[17];
    const float* ln_g   = (const float*)d_in[18];
    const float* ln_b   = (const float*)d_in[19];
    const float* W_ih   = (const float*)d_in[20];
    const float* W_hh   = (const float*)d_in[21];
    const float* b_ih   = (const float*)d_in[22];
    const float* b_hh   = (const float*)d_in[23];
    float* out = (float*)d_out;

    char* wsb = (char*)d_ws;
    float*  xf     = (float*)wsb;  wsb += (size_t)BM2 * DM * 4;   // gcn fp32 out
    ushort* xb     = (ushort*)wsb; wsb += (size_t)BM2 * DM * 2;   // gcn bf16 out
    ushort* t1_bf  = (ushort*)wsb; wsb += (size_t)BM2 * DI * 2;   // relu(ffn1)
    float*  ys     = (float*)wsb;  wsb += (size_t)BM2 * DM * 4;   // pre-LN
    float*  ln_f   = (float*)wsb;  wsb += (size_t)BM2 * DM * 4;   // post-LN fp32
    ushort* ln_bf  = (ushort*)wsb; wsb += (size_t)BM2 * DM * 2;   // post-LN bf16
    float*  sg     = (float*)wsb;  wsb += DM * 4;
    float*  bsumP  = (float*)wsb;  wsb += G4 * 4;
    float*  gaddP  = (float*)wsb;  wsb += G4 * 4;
    ushort* wih_bf = (ushort*)wsb; wsb += (size_t)G4 * DM * 2;
    ushort* whh_bf = (ushort*)wsb; wsb += (size_t)G4 * DM * 2;
    ushort* w1_bf  = (ushort*)wsb; wsb += (size_t)DI * DM * 2;
    ushort* w2_bf  = (ushort*)wsb; wsb += (size_t)DM * DI * 2;
    float*  norms  = (float*)wsb;  wsb += (size_t)NSYM * 4;
    float*  P0f    = (float*)wsb;  wsb += (size_t)BQ * G4 * 4;    // frag-major
    float*  Cf     = (float*)wsb;  wsb += (size_t)BQ * HH * 4;    // frag-major
    ushort* h_bfA  = (ushort*)wsb; wsb += (size_t)BQ * DM * 2;
    ushort* h_bfB  = (ushort*)wsb; wsb += (size_t)BQ * DM * 2;
    float*  h_f    = (float*)wsb;  wsb += (size_t)BQ * DM * 4;

    // catm [8448][256] aliases P0f (dead before lstm_gemm0 writes P0f)
    float* catm = P0f;

    wcvt_kernel<<<G4 * DM / 256, 256, 0, stream>>>(W_ih, W_hh, se_w1, se_w2,
                                                   wih_bf, whh_bf, w1_bf, w2_bf);
    norms_kernel<<<NSYM / 4, 256, 0, stream>>>(emb, norms);
    ne_kernel<<<BQ * 2, 256, 0, stream>>>(q_l_conn, q_r_conn, query, emb, norms, catm);
    ne_kernel<<<BS * 2, 256, 0, stream>>>(s_l_conn, s_r_conn, support, emb, norms,
                                          catm + (size_t)BQ * 2 * DM);
    gcn_kernel<<<(BM2 * 2) / GR, 256, 0, stream>>>(catm, gcn_W, gcn_wb, gcn_b,
                                                   xf, xb);
    { dim3 g1(BM2 / BMT, DI / BNT);
      se_gemm1_kernel<<<g1, 256, 0, stream>>>(xb, w1_bf, se_b1, t1_bf); }
    { dim3 g2(BM2 / BMT, DM / BNT);
      se_gemm2_kernel<<<g2, 256, 0, stream>>>(t1_bf, w2_bf, se_b2, xf, ys); }
    ln_kernel<<<BM2 / LN_ROWS, 256, 0, stream>>>(ys, ln_g, ln_b, ln_f, ln_bf);
    sgw_kernel<<<G4 / 256, 256, 0, stream>>>(ln_f, W_hh, b_ih, b_hh, sg, bsumP, gaddP);

    dim3 ggrid(BQ / BMT, GN / BNT);
    lstm_gemm0_kernel<<<ggrid, 256, 0, stream>>>(ln_bf, wih_bf, bsumP, ln_f,
                                                 P0f, Cf, h_bfA);
    // step 2: A, writes B; step 3: B, writes A; step 4: A, writes h_f (fp32)
    lstm_step_kernel<<<ggrid, 256, 0, stream>>>(h_bfA, whh_bf, P0f, gaddP, ln_f,
                                                Cf, h_bfB, h_f, 0);
    lstm_step_kernel<<<ggrid, 256, 0, stream>>>(h_bfB, whh_bf, P0f, gaddP, ln_f,
                                                Cf, h_bfA, h_f, 0);
    lstm_step_kernel<<<ggrid, 256, 0, stream>>>(h_bfA, whh_bf, P0f, gaddP, ln_f,
                                                Cf, h_bfB, h_f, 1);
    final_kernel<<<BQ / 4, 256, 0, stream>>>(h_f, sg, out);
}

// Round 6
// 439.625 us; speedup vs baseline: 1.1771x; 1.1771x over previous
//
#include <hip/hip_runtime.h>
#include <hip/hip_bf16.h>

#define D   128
#define DM  256
#define DI  512
#define HH  512
#define KNN 10
#define NN  64
#define BQ  4096
#define BS  128
#define BM2 (BQ + BS)        // 4224 batched se rows
#define G4  2048             // 4*HH
#define GN  2048             // LSTM GEMM N
#define GK  256              // LSTM GEMM K
#define NSYM 200000

__device__ __forceinline__ float sigmoidf_(float x) {
    return 1.f / (1.f + __expf(-x));
}
__device__ __forceinline__ float tanh_fast(float x) {
    x = fminf(fmaxf(x, -20.f), 20.f);
    float e = __expf(2.f * x);
    return (e - 1.f) / (e + 1.f);
}
__device__ __forceinline__ ushort f2bf(float x) {
    union { float f; unsigned u; } v; v.f = x;
    unsigned r = (v.u + 0x7fffu + ((v.u >> 16) & 1u)) >> 16;  // RNE
    return (ushort)r;
}

typedef __bf16  bf16x8  __attribute__((ext_vector_type(8)));
typedef float   floatx4 __attribute__((ext_vector_type(4)));

// ---------------- embedding row norms (once) ----------------
__global__ __launch_bounds__(256) void norms_kernel(
    const float* __restrict__ emb, float* __restrict__ norms)
{
    int wave = threadIdx.x >> 6, lane = threadIdx.x & 63;
    int row = blockIdx.x * 4 + wave;
    if (row >= NSYM) return;
    float2 v = *(const float2*)&emb[(size_t)row * D + lane * 2];
    float s = v.x * v.x + v.y * v.y;
    #pragma unroll
    for (int off = 32; off; off >>= 1) s += __shfl_xor(s, off);
    if (lane == 0) norms[row] = sqrtf(s);
}

// ---------------- neighbor encoder: 16-lane-group dot reduction ----------------
// Each wave owns 16 neighbors; the wave's 4 groups of 16 lanes each handle one
// neighbor per batch (lane covers 8 dims). Ladder = 4 xor steps (<16), 6x fewer
// shuffles than the 64-lane ladder. Duplicate ent ids -> bit-identical sims
// (same fixed-order computation), so top_k tie-breaking is preserved.
__global__ __launch_bounds__(256) void ne_kernel(
    const int* __restrict__ conn_l, const int* __restrict__ conn_r,
    const int* __restrict__ ids, const float* __restrict__ emb,
    const float* __restrict__ norms, float* __restrict__ catm_out)
{
    int row = blockIdx.x >> 1;
    int side = blockIdx.x & 1;
    const int* conn = (side ? conn_r : conn_l) + (size_t)row * NN * 2;
    int cid = ids[row * 2 + side];

    __shared__ int   connb[NN * 2];   // [2j]=rel, [2j+1]=ent
    __shared__ float sim[NN];
    __shared__ int   selr[KNN], sele[KNN];

    int tid = threadIdx.x;
    int wave = tid >> 6, lane = tid & 63;
    int grp = lane >> 4, l16 = lane & 15;

    if (tid < NN * 2) connb[tid] = conn[tid];
    const float* cp = &emb[(size_t)cid * D + l16 * 8];
    float4 c4a = *(const float4*)cp;
    float4 c4b = *(const float4*)(cp + 4);
    float cnorm = fmaxf(norms[cid], 1e-8f);
    __syncthreads();

    // prefetch all 4 batches (8 independent float4 loads in flight)
    float4 ea[4], eb[4];
    #pragma unroll
    for (int b = 0; b < 4; b++) {
        int j = wave * 16 + b * 4 + grp;
        int eid = connb[j * 2 + 1];
        const float* ep = &emb[(size_t)eid * D + l16 * 8];
        ea[b] = *(const float4*)ep;
        eb[b] = *(const float4*)(ep + 4);
    }
    #pragma unroll
    for (int b = 0; b < 4; b++) {
        int j = wave * 16 + b * 4 + grp;
        float dot = c4a.x * ea[b].x + c4a.y * ea[b].y + c4a.z * ea[b].z + c4a.w * ea[b].w
                  + c4b.x * eb[b].x + c4b.y * eb[b].y + c4b.z * eb[b].z + c4b.w * eb[b].w;
        #pragma unroll
        for (int off = 8; off; off >>= 1) dot += __shfl_xor(dot, off);
        if (l16 == 0) sim[j] = dot / cnorm;
    }
    __syncthreads();
    if (tid < NN) sim[tid] = sim[tid] / fmaxf(norms[connb[tid * 2 + 1]], 1e-8f);
    __syncthreads();

    // top-10 by (max value, min index) — matches jax.lax.top_k tie-breaking
    if (wave == 0) {
        float s = sim[lane];
        int id = lane;
        for (int k = 0; k < KNN; k++) {
            float bs = s; int bi = id;
            #pragma unroll
            for (int off = 32; off; off >>= 1) {
                float os = __shfl_xor(bs, off);
                int   oi = __shfl_xor(bi, off);
                if (os > bs || (os == bs && oi < bi)) { bs = os; bi = oi; }
            }
            if (lane == 0) { selr[k] = connb[bi * 2]; sele[k] = connb[bi * 2 + 1]; }
            if (id == bi) s = -__builtin_inff();
        }
    }
    __syncthreads();

    float acc = 0.f;
    if (tid < D) {
        #pragma unroll
        for (int k = 0; k < KNN; k++) acc += emb[(size_t)selr[k] * D + tid];
    } else {
        int d = tid - D;
        #pragma unroll
        for (int k = 0; k < KNN; k++) acc += emb[(size_t)sele[k] * D + d];
    }
    catm_out[(size_t)blockIdx.x * DM + tid] = acc * (1.f / KNN);
}

// ---------------- batched GCN transform ----------------
#define GR 16
__global__ __launch_bounds__(256) void gcn_kernel(
    const float* __restrict__ catm, const float* __restrict__ gcn_W,
    const float* __restrict__ gcn_wb, const float* __restrict__ gcn_b,
    float* __restrict__ out, ushort* __restrict__ out_bf)
{
    __shared__ float cs[GR][DM];
    __shared__ float pp[GR][DM];
    int tid = threadIdx.x;
    int m0 = blockIdx.x * GR;
    #pragma unroll
    for (int t = 0; t < 4; t++) {
        int chunk = tid + 256 * t;
        int r = chunk >> 6, c4 = chunk & 63;
        *(float4*)&cs[r][c4 * 4] = *(const float4*)&catm[(size_t)(m0 + r) * DM + c4 * 4];
    }
    __syncthreads();

    int d = tid & 127, half = tid >> 7;
    float a[GR];
    #pragma unroll
    for (int r = 0; r < GR; r++) a[r] = 0.f;
    const float4* W4 = (const float4*)(gcn_W + (size_t)d * DM + half * D);
    for (int f4 = 0; f4 < D / 4; ++f4) {
        float4 w = W4[f4];
        #pragma unroll
        for (int r = 0; r < GR; r++) {
            const float* c = &cs[r][half * D + f4 * 4];
            a[r] += w.x * c[0] + w.y * c[1] + w.z * c[2] + w.w * c[3];
        }
    }
    #pragma unroll
    for (int r = 0; r < GR; r++) pp[r][tid] = a[r];
    __syncthreads();
    if (tid < D) {
        #pragma unroll
        for (int r = 0; r < GR; r++) {
            float h = pp[r][tid] + pp[r][tid + D] + gcn_wb[tid] + gcn_b[tid];
            float th = tanh_fast(h);
            out[(size_t)(m0 + r) * D + tid] = th;
            out_bf[(size_t)(m0 + r) * D + tid] = f2bf(th);
        }
    }
}

// ---------------- weight conversion: gate-interleaved permutation ----------------
// permuted row n: bn=n>>7, r=n&127, half=(r>>6)&1, j=(r>>4)&3, l=r&15
//   -> unit u = bn*32 + half*16 + l, old row = j*512 + u
__global__ __launch_bounds__(256) void wcvt_kernel(
    const float* __restrict__ W_ih, const float* __restrict__ W_hh,
    const float* __restrict__ se_w1, const float* __restrict__ se_w2,
    ushort* __restrict__ wih_bf, ushort* __restrict__ whh_bf,
    ushort* __restrict__ w1_bf, ushort* __restrict__ w2_bf)
{
    int idx = blockIdx.x * 256 + threadIdx.x;   // 0 .. 2048*256-1
    int n = idx >> 8, k = idx & 255;
    int bn = n >> 7, r = n & 127;
    int half = (r >> 6) & 1, j = (r >> 4) & 3, l = r & 15;
    int u = bn * 32 + half * 16 + l;
    int oldrow = j * 512 + u;
    wih_bf[idx] = f2bf(W_ih[(size_t)oldrow * DM + k]);
    whh_bf[idx] = f2bf(W_hh[(size_t)oldrow * HH + k]);
    if (idx < DI * DM) {
        w1_bf[idx] = f2bf(se_w1[idx]);
        w2_bf[idx] = f2bf(se_w2[idx]);
    }
}

// ---------------- bf16 MFMA GEMM tile params ----------------
#define BMT 128
#define BNT 128
#define BKT 64
#define LDP (BKT + 8)

#define GEMM_CORE(AP, BP, KDIM)                                               \
    floatx4 acc[4][4];                                                        \
    _Pragma("unroll")                                                         \
    for (int i = 0; i < 4; i++)                                               \
        _Pragma("unroll")                                                     \
        for (int j = 0; j < 4; j++) acc[i][j] = (floatx4){0.f, 0.f, 0.f, 0.f};\
    for (int k0 = 0; k0 < (KDIM); k0 += BKT) {                                \
        __syncthreads();                                                      \
        _Pragma("unroll")                                                     \
        for (int t = 0; t < 4; t++) {                                         \
            int chunk = tid + 256 * t;                                        \
            int r = chunk >> 3;                                               \
            int c8 = (chunk & 7) * 8;                                         \
            *(uint4*)&As[r][c8] = *(const uint4*)&(AP)[(size_t)(bm * BMT + r) * (KDIM) + k0 + c8]; \
            *(uint4*)&Bs[r][c8] = *(const uint4*)&(BP)[(size_t)(bn * BNT + r) * (KDIM) + k0 + c8]; \
        }                                                                     \
        __syncthreads();                                                      \
        _Pragma("unroll")                                                     \
        for (int kk = 0; kk < BKT; kk += 32) {                                \
            bf16x8 af[4], bf[4];                                              \
            _Pragma("unroll")                                                 \
            for (int i = 0; i < 4; i++)                                       \
                af[i] = *(const bf16x8*)&As[wm + i * 16 + l16][kk + quad * 8];\
            _Pragma("unroll")                                                 \
            for (int j = 0; j < 4; j++)                                       \
                bf[j] = *(const bf16x8*)&Bs[wn + j * 16 + l16][kk + quad * 8];\
            _Pragma("unroll")                                                 \
            for (int i = 0; i < 4; i++)                                       \
                _Pragma("unroll")                                             \
                for (int j = 0; j < 4; j++)                                   \
                    acc[i][j] = __builtin_amdgcn_mfma_f32_16x16x32_bf16(      \
                        af[i], bf[j], acc[i][j], 0, 0, 0);                    \
        }                                                                     \
    }

#define GEMM_PRE()                                                            \
    __shared__ __align__(16) ushort As[BMT][LDP];                             \
    __shared__ __align__(16) ushort Bs[BNT][LDP];                             \
    int tid = threadIdx.x;                                                    \
    int wave = tid >> 6, lane = tid & 63;                                     \
    int quad = lane >> 4, l16 = lane & 15;                                    \
    int bm = blockIdx.x, bn = blockIdx.y;                                     \
    int wm = (wave >> 1) * 64, wn = (wave & 1) * 64;                          \
    (void)wave;

// se GEMM1: t1 = relu(x @ w1^T + b1), bf16 out
__global__ __launch_bounds__(256) void se_gemm1_kernel(
    const ushort* __restrict__ A, const ushort* __restrict__ B,
    const float* __restrict__ b1, ushort* __restrict__ Cbf)
{
    GEMM_PRE();
    GEMM_CORE(A, B, DM);
    #pragma unroll
    for (int i = 0; i < 4; i++) {
        #pragma unroll
        for (int j = 0; j < 4; j++) {
            int row = bm * BMT + wm + i * 16 + quad * 4;
            int col = bn * BNT + wn + j * 16 + l16;
            float bb = b1[col];
            #pragma unroll
            for (int rr = 0; rr < 4; rr++)
                Cbf[(size_t)(row + rr) * DI + col] = f2bf(fmaxf(acc[i][j][rr] + bb, 0.f));
        }
    }
}

// se GEMM2: y = t1 @ w2^T + b2 + x, fp32 out
__global__ __launch_bounds__(256) void se_gemm2_kernel(
    const ushort* __restrict__ A, const ushort* __restrict__ B,
    const float* __restrict__ b2, const float* __restrict__ xres,
    float* __restrict__ C)
{
    GEMM_PRE();
    GEMM_CORE(A, B, DI);
    #pragma unroll
    for (int i = 0; i < 4; i++) {
        #pragma unroll
        for (int j = 0; j < 4; j++) {
            int row = bm * BMT + wm + i * 16 + quad * 4;
            int col = bn * BNT + wn + j * 16 + l16;
            float bb = b2[col];
            #pragma unroll
            for (int rr = 0; rr < 4; rr++)
                C[(size_t)(row + rr) * DM + col] =
                    acc[i][j][rr] + bb + xres[(size_t)(row + rr) * DM + col];
        }
    }
}

// ---------------- LayerNorm ----------------
#define LN_ROWS 8
__global__ __launch_bounds__(256) void ln_kernel(
    const float* __restrict__ ys, const float* __restrict__ g,
    const float* __restrict__ b, float* __restrict__ outf,
    ushort* __restrict__ outbf)
{
    int tid = threadIdx.x;
    int wave = tid >> 6, lane = tid & 63;
    int r0 = blockIdx.x * LN_ROWS;
    for (int rr = 0; rr < 2; ++rr) {
        int r = r0 + wave * 2 + rr;
        float vals[4];
        float s = 0.f;
        #pragma unroll
        for (int e = 0; e < 4; e++) {
            vals[e] = ys[(size_t)r * DM + e * 64 + lane];
            s += vals[e];
        }
        #pragma unroll
        for (int off = 32; off; off >>= 1) s += __shfl_xor(s, off);
        float mu = s * (1.f / DM);
        float v = 0.f;
        #pragma unroll
        for (int e = 0; e < 4; e++) { float dd = vals[e] - mu; v += dd * dd; }
        #pragma unroll
        for (int off = 32; off; off >>= 1) v += __shfl_xor(v, off);
        float rstd = rsqrtf(v * (1.f / DM) + 1e-5f);
        #pragma unroll
        for (int e = 0; e < 4; e++) {
            int dd = e * 64 + lane;
            float ov = (vals[e] - mu) * rstd * g[dd] + b[dd];
            outf[(size_t)r * DM + dd] = ov;
            outbf[(size_t)r * DM + dd] = f2bf(ov);
        }
    }
}

// ------- sg mean + per-gate constants (permuted layout) -------
__global__ __launch_bounds__(256) void sgw_kernel(
    const float* __restrict__ ln_f, const float* __restrict__ W_hh,
    const float* __restrict__ b_ih, const float* __restrict__ b_hh,
    float* __restrict__ sg, float* __restrict__ bsumP, float* __restrict__ gaddP)
{
    __shared__ float s[DM];
    int tid = threadIdx.x;
    float a = 0.f;
    for (int r = 0; r < BS; r++) a += ln_f[(size_t)(BQ + r) * DM + tid];
    a *= (1.f / BS);
    s[tid] = a;
    if (blockIdx.x == 0) sg[tid] = a;
    __syncthreads();

    int grow = blockIdx.x * 256 + tid;     // old gate row 0..2047
    const float4* w4 = (const float4*)(W_hh + (size_t)grow * HH + DM);
    float acc = 0.f;
    for (int f4 = 0; f4 < DM / 4; ++f4) {
        float4 w = w4[f4];
        acc += w.x * s[f4 * 4] + w.y * s[f4 * 4 + 1] + w.z * s[f4 * 4 + 2] + w.w * s[f4 * 4 + 3];
    }
    float bs = b_ih[grow] + b_hh[grow];
    int g = grow >> 9, u = grow & 511;
    int n = (u >> 5) * 128 + ((u >> 4) & 1) * 64 + g * 16 + (u & 15);
    bsumP[n] = bs;
    gaddP[n] = bs + acc;
}

// ---------------- LSTM GEMM step 1 (fused ew1): A=ln_bf, B=wih_perm ----------------
// P0f layout: [tile=bm*16+bn][frag=i*4+j][tid][rr]  (tid-fastest*4 -> float4
// per lane, 16B lane stride = fully coalesced 1KB/wave-instruction)
// Cf layout:  [tile][i][tid][rr]
__global__ __launch_bounds__(256) void lstm_gemm0_kernel(
    const ushort* __restrict__ A, const ushort* __restrict__ B,
    const float* __restrict__ bsumP, const float* __restrict__ lnf,
    float* __restrict__ P0f, float* __restrict__ Cf, ushort* __restrict__ h_out)
{
    GEMM_PRE();
    GEMM_CORE(A, B, GK);
    int u = bn * 32 + (wn ? 16 : 0) + l16;
    size_t tile = (size_t)bm * 16 + bn;
    float b4[4];
    #pragma unroll
    for (int j = 0; j < 4; j++) b4[j] = bsumP[bn * 128 + wn + j * 16 + l16];
    #pragma unroll
    for (int i = 0; i < 4; i++) {
        int row = bm * BMT + wm + i * 16 + quad * 4;
        #pragma unroll
        for (int j = 0; j < 4; j++)
            *(floatx4*)&P0f[((tile * 16 + i * 4 + j) * 256 + tid) * 4] = acc[i][j];
        floatx4 cv4;
        #pragma unroll
        for (int rr = 0; rr < 4; rr++) {
            float iv = acc[i][0][rr] + b4[0];
            float gv = acc[i][2][rr] + b4[2];
            float ov = acc[i][3][rr] + b4[3];
            float cv = sigmoidf_(iv) * tanh_fast(gv);
            cv4[rr] = cv;
            if (bn < 8) {
                float h = lnf[(size_t)(row + rr) * DM + u] + sigmoidf_(ov) * tanh_fast(cv);
                h_out[(size_t)(row + rr) * DM + u] = f2bf(h);
            }
        }
        *(floatx4*)&Cf[((tile * 4 + i) * 256 + tid) * 4] = cv4;
    }
}

// ---------------- LSTM GEMM steps 2..4 (fused ew): A=h_bf(prev), B=whh_perm ----------------
__global__ __launch_bounds__(256) void lstm_step_kernel(
    const ushort* __restrict__ A, const ushort* __restrict__ B,
    const float* __restrict__ P0f, const float* __restrict__ gaddP,
    const float* __restrict__ lnf, float* __restrict__ Cf,
    ushort* __restrict__ h_out, float* __restrict__ hf_out, int last)
{
    GEMM_PRE();
    GEMM_CORE(A, B, GK);
    int u = bn * 32 + (wn ? 16 : 0) + l16;
    size_t tile = (size_t)bm * 16 + bn;
    float g4[4];
    #pragma unroll
    for (int j = 0; j < 4; j++) g4[j] = gaddP[bn * 128 + wn + j * 16 + l16];
    #pragma unroll
    for (int i = 0; i < 4; i++) {
        int row = bm * BMT + wm + i * 16 + quad * 4;
        floatx4 p0[4];
        #pragma unroll
        for (int j = 0; j < 4; j++)
            p0[j] = *(const floatx4*)&P0f[((tile * 16 + i * 4 + j) * 256 + tid) * 4];
        floatx4 cprev = *(const floatx4*)&Cf[((tile * 4 + i) * 256 + tid) * 4];
        floatx4 cnew;
        #pragma unroll
        for (int rr = 0; rr < 4; rr++) {
            float iv = acc[i][0][rr] + p0[0][rr] + g4[0];
            float fv = acc[i][1][rr] + p0[1][rr] + g4[1];
            float gv = acc[i][2][rr] + p0[2][rr] + g4[2];
            float ov = acc[i][3][rr] + p0[3][rr] + g4[3];
            float cv = sigmoidf_(fv) * cprev[rr] + sigmoidf_(iv) * tanh_fast(gv);
            cnew[rr] = cv;
            if (bn < 8) {
                float h = lnf[(size_t)(row + rr) * DM + u] + sigmoidf_(ov) * tanh_fast(cv);
                if (last) hf_out[(size_t)(row + rr) * DM + u] = h;
                else      h_out[(size_t)(row + rr) * DM + u] = f2bf(h);
            }
        }
        *(floatx4*)&Cf[((tile * 4 + i) * 256 + tid) * 4] = cnew;
    }
}

// ---------------- final cosine ----------------
__global__ __launch_bounds__(256) void final_kernel(
    const float* __restrict__ h_ws, const float* __restrict__ sg,
    float* __restrict__ outp)
{
    __shared__ float sgs[DM];
    int tid = threadIdx.x;
    sgs[tid] = sg[tid];
    __syncthreads();
    int wave = tid >> 6, lane = tid & 63;
    float sn = 0.f;
    #pragma unroll
    for (int e = 0; e < 4; e++) { float v = sgs[e * 64 + lane]; sn += v * v; }
    #pragma unroll
    for (int off = 32; off; off >>= 1) sn += __shfl_xor(sn, off);
    float sgnorm = fmaxf(sqrtf(sn), 1e-12f);

    int row = blockIdx.x * 4 + wave;
    const float* h = h_ws + (size_t)row * DM;
    float dot = 0.f, hn = 0.f;
    #pragma unroll
    for (int e = 0; e < 4; e++) {
        float hv = h[e * 64 + lane];
        dot += hv * sgs[e * 64 + lane];
        hn += hv * hv;
    }
    #pragma unroll
    for (int off = 32; off; off >>= 1) { dot += __shfl_xor(dot, off); hn += __shfl_xor(hn, off); }
    if (lane == 0) outp[row] = dot / (fmaxf(sqrtf(hn), 1e-12f) * sgnorm);
}

extern "C" void kernel_launch(void* const* d_in, const int* in_sizes, int n_in,
                              void* d_out, int out_size, void* d_ws, size_t ws_size,
                              hipStream_t stream)
{
    const int* query    = (const int*)d_in[0];
    const int* support  = (const int*)d_in[1];
    const int* q_l_conn = (const int*)d_in[2];
    const int* q_r_conn = (const int*)d_in[4];
    const int* s_l_conn = (const int*)d_in[6];
    const int* s_r_conn = (const int*)d_in[8];
    const float* emb    = (const float*)d_in[10];
    const float* gcn_W  = (const float*)d_in[11];
    const float* gcn_wb = (const float*)d_in[12];
    const float* gcn_b  = (const float*)d_in[13];
    const float* se_w1  = (const float*)d_in[14];
    const float* se_b1  = (const float*)d_in[15];
    const float* se_w2  = (const float*)d_in[16];
    const float* se_b2  = (const float*)d_in[17];
    const float* ln_g   = (const float*)d_in[18];
    const float* ln_b   = (const float*)d_in[19];
    const float* W_ih   = (const float*)d_in[20];
    const float* W_hh   = (const float*)d_in[21];
    const float* b_ih   = (const float*)d_in[22];
    const float* b_hh   = (const float*)d_in[23];
    float* out = (float*)d_out;

    char* wsb = (char*)d_ws;
    float*  xf     = (float*)wsb;  wsb += (size_t)BM2 * DM * 4;   // gcn fp32 out
    ushort* xb     = (ushort*)wsb; wsb += (size_t)BM2 * DM * 2;   // gcn bf16 out
    ushort* t1_bf  = (ushort*)wsb; wsb += (size_t)BM2 * DI * 2;   // relu(ffn1)
    float*  ys     = (float*)wsb;  wsb += (size_t)BM2 * DM * 4;   // pre-LN
    float*  ln_f   = (float*)wsb;  wsb += (size_t)BM2 * DM * 4;   // post-LN fp32
    ushort* ln_bf  = (ushort*)wsb; wsb += (size_t)BM2 * DM * 2;   // post-LN bf16
    float*  sg     = (float*)wsb;  wsb += DM * 4;
    float*  bsumP  = (float*)wsb;  wsb += G4 * 4;
    float*  gaddP  = (float*)wsb;  wsb += G4 * 4;
    ushort* wih_bf = (ushort*)wsb; wsb += (size_t)G4 * DM * 2;
    ushort* whh_bf = (ushort*)wsb; wsb += (size_t)G4 * DM * 2;
    ushort* w1_bf  = (ushort*)wsb; wsb += (size_t)DI * DM * 2;
    ushort* w2_bf  = (ushort*)wsb; wsb += (size_t)DM * DI * 2;
    float*  norms  = (float*)wsb;  wsb += (size_t)NSYM * 4;
    float*  P0f    = (float*)wsb;  wsb += (size_t)BQ * G4 * 4;    // frag tid-fast
    float*  Cf     = (float*)wsb;  wsb += (size_t)BQ * HH * 4;    // frag tid-fast
    ushort* h_bfA  = (ushort*)wsb; wsb += (size_t)BQ * DM * 2;
    ushort* h_bfB  = (ushort*)wsb; wsb += (size_t)BQ * DM * 2;
    float*  h_f    = (float*)wsb;  wsb += (size_t)BQ * DM * 4;

    // catm [8448][256] aliases P0f (dead before lstm_gemm0 writes P0f)
    float* catm = P0f;

    wcvt_kernel<<<G4 * DM / 256, 256, 0, stream>>>(W_ih, W_hh, se_w1, se_w2,
                                                   wih_bf, whh_bf, w1_bf, w2_bf);
    norms_kernel<<<NSYM / 4, 256, 0, stream>>>(emb, norms);
    ne_kernel<<<BQ * 2, 256, 0, stream>>>(q_l_conn, q_r_conn, query, emb, norms, catm);
    ne_kernel<<<BS * 2, 256, 0, stream>>>(s_l_conn, s_r_conn, support, emb, norms,
                                          catm + (size_t)BQ * 2 * DM);
    gcn_kernel<<<(BM2 * 2) / GR, 256, 0, stream>>>(catm, gcn_W, gcn_wb, gcn_b,
                                                   xf, xb);
    { dim3 g1(BM2 / BMT, DI / BNT);
      se_gemm1_kernel<<<g1, 256, 0, stream>>>(xb, w1_bf, se_b1, t1_bf); }
    { dim3 g2(BM2 / BMT, DM / BNT);
      se_gemm2_kernel<<<g2, 256, 0, stream>>>(t1_bf, w2_bf, se_b2, xf, ys); }
    ln_kernel<<<BM2 / LN_ROWS, 256, 0, stream>>>(ys, ln_g, ln_b, ln_f, ln_bf);
    sgw_kernel<<<G4 / 256, 256, 0, stream>>>(ln_f, W_hh, b_ih, b_hh, sg, bsumP, gaddP);

    dim3 ggrid(BQ / BMT, GN / BNT);
    lstm_gemm0_kernel<<<ggrid, 256, 0, stream>>>(ln_bf, wih_bf, bsumP, ln_f,
                                                 P0f, Cf, h_bfA);
    lstm_step_kernel<<<ggrid, 256, 0, stream>>>(h_bfA, whh_bf, P0f, gaddP, ln_f,
                                                Cf, h_bfB, h_f, 0);
    lstm_step_kernel<<<ggrid, 256, 0, stream>>>(h_bfB, whh_bf, P0f, gaddP, ln_f,
                                                Cf, h_bfA, h_f, 0);
    lstm_step_kernel<<<ggrid, 256, 0, stream>>>(h_bfA, whh_bf, P0f, gaddP, ln_f,
                                                Cf, h_bfB, h_f, 1);
    final_kernel<<<BQ / 4, 256, 0, stream>>>(h_f, sg, out);
}

// Round 7
// 407.192 us; speedup vs baseline: 1.2708x; 1.0797x over previous
//
#include <hip/hip_runtime.h>
#include <hip/hip_bf16.h>

#define D   128
#define DM  256
#define DI  512
#define HH  512
#define KNN 10
#define NN  64
#define BQ  4096
#define BS  128
#define BM2 (BQ + BS)        // 4224 batched se rows
#define G2  1024             // live LSTM gate rows (4 gates x 256 live units)
#define GK  256              // LSTM GEMM K
#define NSYM 200000

__device__ __forceinline__ float sigmoidf_(float x) {
    return 1.f / (1.f + __expf(-x));
}
__device__ __forceinline__ float tanh_fast(float x) {
    x = fminf(fmaxf(x, -20.f), 20.f);
    float e = __expf(2.f * x);
    return (e - 1.f) / (e + 1.f);
}
__device__ __forceinline__ ushort f2bf(float x) {
    union { float f; unsigned u; } v; v.f = x;
    unsigned r = (v.u + 0x7fffu + ((v.u >> 16) & 1u)) >> 16;  // RNE
    return (ushort)r;
}

typedef __bf16  bf16x8  __attribute__((ext_vector_type(8)));
typedef float   floatx4 __attribute__((ext_vector_type(4)));

// ---------------- prologue: emb norms + weight conversion + bsumP ----------------
// grid = 50000 (norms, 4 rows/block) + 1024 (wih/whh permuted rows) + 512 (se w1/w2)
__global__ __launch_bounds__(256) void prep_kernel(
    const float* __restrict__ emb, float* __restrict__ norms,
    const float* __restrict__ W_ih, const float* __restrict__ W_hh,
    const float* __restrict__ b_ih, const float* __restrict__ b_hh,
    const float* __restrict__ se_w1, const float* __restrict__ se_w2,
    ushort* __restrict__ wih_bf, ushort* __restrict__ whh_bf,
    float* __restrict__ bsumP, ushort* __restrict__ w1_bf,
    ushort* __restrict__ w2_bf)
{
    int bid = blockIdx.x;
    int tid = threadIdx.x;
    if (bid < 50000) {
        int wave = tid >> 6, lane = tid & 63;
        int row = bid * 4 + wave;
        float2 v = *(const float2*)&emb[(size_t)row * D + lane * 2];
        float s = v.x * v.x + v.y * v.y;
        #pragma unroll
        for (int off = 32; off; off >>= 1) s += __shfl_xor(s, off);
        if (lane == 0) norms[row] = sqrtf(s);
    } else if (bid < 50000 + G2) {
        // permuted row n: bn=n>>7, r=n&127, half=(r>>6)&1, j=(r>>4)&3, l=r&15
        //   unit u = bn*32 + half*16 + l (0..255), old gate row = j*512 + u
        int n = bid - 50000;
        int bn = n >> 7, r = n & 127;
        int half = (r >> 6) & 1, j = (r >> 4) & 3, l = r & 15;
        int u = bn * 32 + half * 16 + l;
        int oldrow = j * 512 + u;
        wih_bf[n * 256 + tid] = f2bf(W_ih[(size_t)oldrow * DM + tid]);
        whh_bf[n * 256 + tid] = f2bf(W_hh[(size_t)oldrow * HH + tid]);
        if (tid == 0) bsumP[n] = b_ih[oldrow] + b_hh[oldrow];
    } else {
        int idx = (bid - 50000 - G2) * 256 + tid;   // 0..131071
        w1_bf[idx] = f2bf(se_w1[idx]);
        w2_bf[idx] = f2bf(se_w2[idx]);
    }
}

// ---------------- neighbor encoder (merged q+s): register fragments ----------------
// grid = BQ*2 + BS*2 = 8448; block b<8192 -> query pair, else support pair.
__global__ __launch_bounds__(256) void ne_kernel(
    const int* __restrict__ q_l, const int* __restrict__ q_r,
    const int* __restrict__ q_ids,
    const int* __restrict__ s_l, const int* __restrict__ s_r,
    const int* __restrict__ s_ids,
    const float* __restrict__ emb, const float* __restrict__ norms,
    float* __restrict__ catm_out)
{
    int bid = blockIdx.x;
    const int *conn_l, *conn_r, *ids;
    int row;
    if (bid < BQ * 2) { conn_l = q_l; conn_r = q_r; ids = q_ids; row = bid >> 1; }
    else { conn_l = s_l; conn_r = s_r; ids = s_ids; row = (bid - BQ * 2) >> 1; }
    int side = bid & 1;
    const int* conn = (side ? conn_r : conn_l) + (size_t)row * NN * 2;
    int cid = ids[row * 2 + side];

    __shared__ int   connb[NN * 2];
    __shared__ float sim[NN];
    __shared__ int   selr[KNN], sele[KNN];

    int tid = threadIdx.x;
    int wave = tid >> 6, lane = tid & 63;
    int grp = lane >> 4, l16 = lane & 15;

    if (tid < NN * 2) connb[tid] = conn[tid];
    const float* cp = &emb[(size_t)cid * D + l16 * 8];
    float4 c4a = *(const float4*)cp;
    float4 c4b = *(const float4*)(cp + 4);
    float cnorm = fmaxf(norms[cid], 1e-8f);
    __syncthreads();

    float4 ea[4], eb[4];
    #pragma unroll
    for (int b = 0; b < 4; b++) {
        int j = wave * 16 + b * 4 + grp;
        int eid = connb[j * 2 + 1];
        const float* ep = &emb[(size_t)eid * D + l16 * 8];
        ea[b] = *(const float4*)ep;
        eb[b] = *(const float4*)(ep + 4);
    }
    #pragma unroll
    for (int b = 0; b < 4; b++) {
        int j = wave * 16 + b * 4 + grp;
        float dot = c4a.x * ea[b].x + c4a.y * ea[b].y + c4a.z * ea[b].z + c4a.w * ea[b].w
                  + c4b.x * eb[b].x + c4b.y * eb[b].y + c4b.z * eb[b].z + c4b.w * eb[b].w;
        #pragma unroll
        for (int off = 8; off; off >>= 1) dot += __shfl_xor(dot, off);
        if (l16 == 0) sim[j] = dot / cnorm;
    }
    __syncthreads();
    if (tid < NN) sim[tid] = sim[tid] / fmaxf(norms[connb[tid * 2 + 1]], 1e-8f);
    __syncthreads();

    // top-10 by (max value, min index) — matches jax.lax.top_k tie-breaking
    if (wave == 0) {
        float s = sim[lane];
        int id = lane;
        for (int k = 0; k < KNN; k++) {
            float bs = s; int bi = id;
            #pragma unroll
            for (int off = 32; off; off >>= 1) {
                float os = __shfl_xor(bs, off);
                int   oi = __shfl_xor(bi, off);
                if (os > bs || (os == bs && oi < bi)) { bs = os; bi = oi; }
            }
            if (lane == 0) { selr[k] = connb[bi * 2]; sele[k] = connb[bi * 2 + 1]; }
            if (id == bi) s = -__builtin_inff();
        }
    }
    __syncthreads();

    float acc = 0.f;
    if (tid < D) {
        #pragma unroll
        for (int k = 0; k < KNN; k++) acc += emb[(size_t)selr[k] * D + tid];
    } else {
        int d = tid - D;
        #pragma unroll
        for (int k = 0; k < KNN; k++) acc += emb[(size_t)sele[k] * D + d];
    }
    catm_out[(size_t)bid * DM + tid] = acc * (1.f / KNN);
}

// ---------------- batched GCN transform ----------------
#define GR 16
__global__ __launch_bounds__(256) void gcn_kernel(
    const float* __restrict__ catm, const float* __restrict__ gcn_W,
    const float* __restrict__ gcn_wb, const float* __restrict__ gcn_b,
    float* __restrict__ out, ushort* __restrict__ out_bf)
{
    __shared__ float cs[GR][DM];
    __shared__ float pp[GR][DM];
    int tid = threadIdx.x;
    int m0 = blockIdx.x * GR;
    #pragma unroll
    for (int t = 0; t < 4; t++) {
        int chunk = tid + 256 * t;
        int r = chunk >> 6, c4 = chunk & 63;
        *(float4*)&cs[r][c4 * 4] = *(const float4*)&catm[(size_t)(m0 + r) * DM + c4 * 4];
    }
    __syncthreads();

    int d = tid & 127, half = tid >> 7;
    float a[GR];
    #pragma unroll
    for (int r = 0; r < GR; r++) a[r] = 0.f;
    const float4* W4 = (const float4*)(gcn_W + (size_t)d * DM + half * D);
    for (int f4 = 0; f4 < D / 4; ++f4) {
        float4 w = W4[f4];
        #pragma unroll
        for (int r = 0; r < GR; r++) {
            const float* c = &cs[r][half * D + f4 * 4];
            a[r] += w.x * c[0] + w.y * c[1] + w.z * c[2] + w.w * c[3];
        }
    }
    #pragma unroll
    for (int r = 0; r < GR; r++) pp[r][tid] = a[r];
    __syncthreads();
    if (tid < D) {
        #pragma unroll
        for (int r = 0; r < GR; r++) {
            float h = pp[r][tid] + pp[r][tid + D] + gcn_wb[tid] + gcn_b[tid];
            float th = tanh_fast(h);
            out[(size_t)(m0 + r) * D + tid] = th;
            out_bf[(size_t)(m0 + r) * D + tid] = f2bf(th);
        }
    }
}

// ---------------- bf16 MFMA GEMM tile params ----------------
#define BMT 128
#define BNT 128
#define BKT 64
#define LDP (BKT + 8)

#define GEMM_CORE(AP, BP, KDIM)                                               \
    floatx4 acc[4][4];                                                        \
    _Pragma("unroll")                                                         \
    for (int i = 0; i < 4; i++)                                               \
        _Pragma("unroll")                                                     \
        for (int j = 0; j < 4; j++) acc[i][j] = (floatx4){0.f, 0.f, 0.f, 0.f};\
    for (int k0 = 0; k0 < (KDIM); k0 += BKT) {                                \
        __syncthreads();                                                      \
        _Pragma("unroll")                                                     \
        for (int t = 0; t < 4; t++) {                                         \
            int chunk = tid + 256 * t;                                        \
            int r = chunk >> 3;                                               \
            int c8 = (chunk & 7) * 8;                                         \
            *(uint4*)&As[r][c8] = *(const uint4*)&(AP)[(size_t)(bm * BMT + r) * (KDIM) + k0 + c8]; \
            *(uint4*)&Bs[r][c8] = *(const uint4*)&(BP)[(size_t)(bn * BNT + r) * (KDIM) + k0 + c8]; \
        }                                                                     \
        __syncthreads();                                                      \
        _Pragma("unroll")                                                     \
        for (int kk = 0; kk < BKT; kk += 32) {                                \
            bf16x8 af[4], bf[4];                                              \
            _Pragma("unroll")                                                 \
            for (int i = 0; i < 4; i++)                                       \
                af[i] = *(const bf16x8*)&As[wm + i * 16 + l16][kk + quad * 8];\
            _Pragma("unroll")                                                 \
            for (int j = 0; j < 4; j++)                                       \
                bf[j] = *(const bf16x8*)&Bs[wn + j * 16 + l16][kk + quad * 8];\
            _Pragma("unroll")                                                 \
            for (int i = 0; i < 4; i++)                                       \
                _Pragma("unroll")                                             \
                for (int j = 0; j < 4; j++)                                   \
                    acc[i][j] = __builtin_amdgcn_mfma_f32_16x16x32_bf16(      \
                        af[i], bf[j], acc[i][j], 0, 0, 0);                    \
        }                                                                     \
    }

#define GEMM_PRE()                                                            \
    __shared__ __align__(16) ushort As[BMT][LDP];                             \
    __shared__ __align__(16) ushort Bs[BNT][LDP];                             \
    int tid = threadIdx.x;                                                    \
    int wave = tid >> 6, lane = tid & 63;                                     \
    int quad = lane >> 4, l16 = lane & 15;                                    \
    int bm = blockIdx.x, bn = blockIdx.y;                                     \
    int wm = (wave >> 1) * 64, wn = (wave & 1) * 64;                          \
    (void)wave;

// se GEMM1: t1 = relu(x @ w1^T + b1), bf16 out
__global__ __launch_bounds__(256) void se_gemm1_kernel(
    const ushort* __restrict__ A, const ushort* __restrict__ B,
    const float* __restrict__ b1, ushort* __restrict__ Cbf)
{
    GEMM_PRE();
    GEMM_CORE(A, B, DM);
    #pragma unroll
    for (int i = 0; i < 4; i++) {
        #pragma unroll
        for (int j = 0; j < 4; j++) {
            int row = bm * BMT + wm + i * 16 + quad * 4;
            int col = bn * BNT + wn + j * 16 + l16;
            float bb = b1[col];
            #pragma unroll
            for (int rr = 0; rr < 4; rr++)
                Cbf[(size_t)(row + rr) * DI + col] = f2bf(fmaxf(acc[i][j][rr] + bb, 0.f));
        }
    }
}

// se GEMM2: y = t1 @ w2^T + b2 + x, fp32 out
__global__ __launch_bounds__(256) void se_gemm2_kernel(
    const ushort* __restrict__ A, const ushort* __restrict__ B,
    const float* __restrict__ b2, const float* __restrict__ xres,
    float* __restrict__ C)
{
    GEMM_PRE();
    GEMM_CORE(A, B, DI);
    #pragma unroll
    for (int i = 0; i < 4; i++) {
        #pragma unroll
        for (int j = 0; j < 4; j++) {
            int row = bm * BMT + wm + i * 16 + quad * 4;
            int col = bn * BNT + wn + j * 16 + l16;
            float bb = b2[col];
            #pragma unroll
            for (int rr = 0; rr < 4; rr++)
                C[(size_t)(row + rr) * DM + col] =
                    acc[i][j][rr] + bb + xres[(size_t)(row + rr) * DM + col];
        }
    }
}

// ---------------- LayerNorm ----------------
#define LN_ROWS 8
__global__ __launch_bounds__(256) void ln_kernel(
    const float* __restrict__ ys, const float* __restrict__ g,
    const float* __restrict__ b, float* __restrict__ outf,
    ushort* __restrict__ outbf)
{
    int tid = threadIdx.x;
    int wave = tid >> 6, lane = tid & 63;
    int r0 = blockIdx.x * LN_ROWS;
    for (int rr = 0; rr < 2; ++rr) {
        int r = r0 + wave * 2 + rr;
        float vals[4];
        float s = 0.f;
        #pragma unroll
        for (int e = 0; e < 4; e++) {
            vals[e] = ys[(size_t)r * DM + e * 64 + lane];
            s += vals[e];
        }
        #pragma unroll
        for (int off = 32; off; off >>= 1) s += __shfl_xor(s, off);
        float mu = s * (1.f / DM);
        float v = 0.f;
        #pragma unroll
        for (int e = 0; e < 4; e++) { float dd = vals[e] - mu; v += dd * dd; }
        #pragma unroll
        for (int off = 32; off; off >>= 1) v += __shfl_xor(v, off);
        float rstd = rsqrtf(v * (1.f / DM) + 1e-5f);
        #pragma unroll
        for (int e = 0; e < 4; e++) {
            int dd = e * 64 + lane;
            float ov = (vals[e] - mu) * rstd * g[dd] + b[dd];
            outf[(size_t)r * DM + dd] = ov;
            outbf[(size_t)r * DM + dd] = f2bf(ov);
        }
    }
}

// ------- sg mean + per-gate gadd constants (permuted, live gates only) -------
// grid = 4 blocks x 256 threads covering 1024 live gate rows
__global__ __launch_bounds__(256) void sgw_kernel(
    const float* __restrict__ ln_f, const float* __restrict__ W_hh,
    const float* __restrict__ b_ih, const float* __restrict__ b_hh,
    float* __restrict__ sg, float* __restrict__ gaddP)
{
    __shared__ float s[DM];
    int tid = threadIdx.x;
    float a = 0.f;
    for (int r = 0; r < BS; r++) a += ln_f[(size_t)(BQ + r) * DM + tid];
    a *= (1.f / BS);
    s[tid] = a;
    if (blockIdx.x == 0) sg[tid] = a;
    __syncthreads();

    int idx = blockIdx.x * 256 + tid;      // 0..1023
    int g = idx >> 8, u = idx & 255;       // gate, live unit
    int oldrow = g * 512 + u;
    const float4* w4 = (const float4*)(W_hh + (size_t)oldrow * HH + DM);
    float acc = 0.f;
    for (int f4 = 0; f4 < DM / 4; ++f4) {
        float4 w = w4[f4];
        acc += w.x * s[f4 * 4] + w.y * s[f4 * 4 + 1] + w.z * s[f4 * 4 + 2] + w.w * s[f4 * 4 + 3];
    }
    float bs = b_ih[oldrow] + b_hh[oldrow];
    int n = (u >> 5) * 128 + ((u >> 4) & 1) * 64 + g * 16 + (u & 15);
    gaddP[n] = bs + acc;
}

// ---------------- LSTM GEMM step 1 (fused ew1): A=ln_bf, B=wih_perm ----------------
// N = 1024 live gates, grid (32, 8).
// P0f layout: [tile=bm*8+bn][frag=i*4+j][tid][rr] (tid-fastest, coalesced)
// Cf layout:  [tile][i][tid][rr]
__global__ __launch_bounds__(256) void lstm_gemm0_kernel(
    const ushort* __restrict__ A, const ushort* __restrict__ B,
    const float* __restrict__ bsumP, const float* __restrict__ lnf,
    float* __restrict__ P0f, float* __restrict__ Cf, ushort* __restrict__ h_out)
{
    GEMM_PRE();
    GEMM_CORE(A, B, GK);
    int u = bn * 32 + (wn ? 16 : 0) + l16;
    size_t tile = (size_t)bm * 8 + bn;
    float b4[4];
    #pragma unroll
    for (int j = 0; j < 4; j++) b4[j] = bsumP[bn * 128 + wn + j * 16 + l16];
    #pragma unroll
    for (int i = 0; i < 4; i++) {
        int row = bm * BMT + wm + i * 16 + quad * 4;
        #pragma unroll
        for (int j = 0; j < 4; j++)
            *(floatx4*)&P0f[((tile * 16 + i * 4 + j) * 256 + tid) * 4] = acc[i][j];
        floatx4 cv4;
        #pragma unroll
        for (int rr = 0; rr < 4; rr++) {
            float iv = acc[i][0][rr] + b4[0];
            float gv = acc[i][2][rr] + b4[2];
            float ov = acc[i][3][rr] + b4[3];
            float cv = sigmoidf_(iv) * tanh_fast(gv);
            cv4[rr] = cv;
            float h = lnf[(size_t)(row + rr) * DM + u] + sigmoidf_(ov) * tanh_fast(cv);
            h_out[(size_t)(row + rr) * DM + u] = f2bf(h);
        }
        *(floatx4*)&Cf[((tile * 4 + i) * 256 + tid) * 4] = cv4;
    }
}

// ---------------- LSTM GEMM steps 2..4 (fused ew): A=h_bf(prev), B=whh_perm ----------------
__global__ __launch_bounds__(256) void lstm_step_kernel(
    const ushort* __restrict__ A, const ushort* __restrict__ B,
    const float* __restrict__ P0f, const float* __restrict__ gaddP,
    const float* __restrict__ lnf, float* __restrict__ Cf,
    ushort* __restrict__ h_out, float* __restrict__ hf_out, int last)
{
    GEMM_PRE();
    GEMM_CORE(A, B, GK);
    int u = bn * 32 + (wn ? 16 : 0) + l16;
    size_t tile = (size_t)bm * 8 + bn;
    float g4[4];
    #pragma unroll
    for (int j = 0; j < 4; j++) g4[j] = gaddP[bn * 128 + wn + j * 16 + l16];
    #pragma unroll
    for (int i = 0; i < 4; i++) {
        int row = bm * BMT + wm + i * 16 + quad * 4;
        floatx4 p0[4];
        #pragma unroll
        for (int j = 0; j < 4; j++)
            p0[j] = *(const floatx4*)&P0f[((tile * 16 + i * 4 + j) * 256 + tid) * 4];
        floatx4 cprev = *(const floatx4*)&Cf[((tile * 4 + i) * 256 + tid) * 4];
        floatx4 cnew;
        #pragma unroll
        for (int rr = 0; rr < 4; rr++) {
            float iv = acc[i][0][rr] + p0[0][rr] + g4[0];
            float fv = acc[i][1][rr] + p0[1][rr] + g4[1];
            float gv = acc[i][2][rr] + p0[2][rr] + g4[2];
            float ov = acc[i][3][rr] + p0[3][rr] + g4[3];
            float cv = sigmoidf_(fv) * cprev[rr] + sigmoidf_(iv) * tanh_fast(gv);
            cnew[rr] = cv;
            float h = lnf[(size_t)(row + rr) * DM + u] + sigmoidf_(ov) * tanh_fast(cv);
            if (last) hf_out[(size_t)(row + rr) * DM + u] = h;
            else      h_out[(size_t)(row + rr) * DM + u] = f2bf(h);
        }
        *(floatx4*)&Cf[((tile * 4 + i) * 256 + tid) * 4] = cnew;
    }
}

// ---------------- final cosine ----------------
__global__ __launch_bounds__(256) void final_kernel(
    const float* __restrict__ h_ws, const float* __restrict__ sg,
    float* __restrict__ outp)
{
    __shared__ float sgs[DM];
    int tid = threadIdx.x;
    sgs[tid] = sg[tid];
    __syncthreads();
    int wave = tid >> 6, lane = tid & 63;
    float sn = 0.f;
    #pragma unroll
    for (int e = 0; e < 4; e++) { float v = sgs[e * 64 + lane]; sn += v * v; }
    #pragma unroll
    for (int off = 32; off; off >>= 1) sn += __shfl_xor(sn, off);
    float sgnorm = fmaxf(sqrtf(sn), 1e-12f);

    int row = blockIdx.x * 4 + wave;
    const float* h = h_ws + (size_t)row * DM;
    float dot = 0.f, hn = 0.f;
    #pragma unroll
    for (int e = 0; e < 4; e++) {
        float hv = h[e * 64 + lane];
        dot += hv * sgs[e * 64 + lane];
        hn += hv * hv;
    }
    #pragma unroll
    for (int off = 32; off; off >>= 1) { dot += __shfl_xor(dot, off); hn += __shfl_xor(hn, off); }
    if (lane == 0) outp[row] = dot / (fmaxf(sqrtf(hn), 1e-12f) * sgnorm);
}

extern "C" void kernel_launch(void* const* d_in, const int* in_sizes, int n_in,
                              void* d_out, int out_size, void* d_ws, size_t ws_size,
                              hipStream_t stream)
{
    const int* query    = (const int*)d_in[0];
    const int* support  = (const int*)d_in[1];
    const int* q_l_conn = (const int*)d_in[2];
    const int* q_r_conn = (const int*)d_in[4];
    const int* s_l_conn = (const int*)d_in[6];
    const int* s_r_conn = (const int*)d_in[8];
    const float* emb    = (const float*)d_in[10];
    const float* gcn_W  = (const float*)d_in[11];
    const float* gcn_wb = (const float*)d_in[12];
    const float* gcn_b  = (const float*)d_in[13];
    const float* se_w1  = (const float*)d_in[14];
    const float* se_b1  = (const float*)d_in[15];
    const float* se_w2  = (const float*)d_in[16];
    const float* se_b2  = (const float*)d_in[17];
    const float* ln_g   = (const float*)d_in[18];
    const float* ln_b   = (const float*)d_in[19];
    const float* W_ih   = (const float*)d_in[20];
    const float* W_hh   = (const float*)d_in[21];
    const float* b_ih   = (const float*)d_in[22];
    const float* b_hh   = (const float*)d_in[23];
    float* out = (float*)d_out;

    char* wsb = (char*)d_ws;
    float*  xf     = (float*)wsb;  wsb += (size_t)BM2 * DM * 4;   // gcn fp32 out
    ushort* xb     = (ushort*)wsb; wsb += (size_t)BM2 * DM * 2;   // gcn bf16 out
    ushort* t1_bf  = (ushort*)wsb; wsb += (size_t)BM2 * DI * 2;   // relu(ffn1)
    float*  ys     = (float*)wsb;  wsb += (size_t)BM2 * DM * 4;   // pre-LN
    float*  ln_f   = (float*)wsb;  wsb += (size_t)BM2 * DM * 4;   // post-LN fp32
    ushort* ln_bf  = (ushort*)wsb; wsb += (size_t)BM2 * DM * 2;   // post-LN bf16
    float*  sg     = (float*)wsb;  wsb += DM * 4;
    float*  bsumP  = (float*)wsb;  wsb += G2 * 4;
    float*  gaddP  = (float*)wsb;  wsb += G2 * 4;
    ushort* wih_bf = (ushort*)wsb; wsb += (size_t)G2 * DM * 2;
    ushort* whh_bf = (ushort*)wsb; wsb += (size_t)G2 * DM * 2;
    ushort* w1_bf  = (ushort*)wsb; wsb += (size_t)DI * DM * 2;
    ushort* w2_bf  = (ushort*)wsb; wsb += (size_t)DM * DI * 2;
    float*  norms  = (float*)wsb;  wsb += (size_t)NSYM * 4;
    float*  P0f    = (float*)wsb;  wsb += (size_t)BQ * G2 * 4;    // frag tid-fast
    float*  Cf     = (float*)wsb;  wsb += (size_t)BQ * DM * 4;    // live c only
    ushort* h_bfA  = (ushort*)wsb; wsb += (size_t)BQ * DM * 2;
    ushort* h_bfB  = (ushort*)wsb; wsb += (size_t)BQ * DM * 2;
    float*  h_f    = (float*)wsb;  wsb += (size_t)BQ * DM * 4;

    // catm [8448][256] (8.65 MB) aliases P0f (16 MB; dead until lstm_gemm0)
    float* catm = P0f;

    prep_kernel<<<50000 + G2 + 512, 256, 0, stream>>>(
        emb, norms, W_ih, W_hh, b_ih, b_hh, se_w1, se_w2,
        wih_bf, whh_bf, bsumP, w1_bf, w2_bf);
    ne_kernel<<<BQ * 2 + BS * 2, 256, 0, stream>>>(
        q_l_conn, q_r_conn, query, s_l_conn, s_r_conn, support,
        emb, norms, catm);
    gcn_kernel<<<(BM2 * 2) / GR, 256, 0, stream>>>(catm, gcn_W, gcn_wb, gcn_b,
                                                   xf, xb);
    { dim3 g1(BM2 / BMT, DI / BNT);
      se_gemm1_kernel<<<g1, 256, 0, stream>>>(xb, w1_bf, se_b1, t1_bf); }
    { dim3 g2(BM2 / BMT, DM / BNT);
      se_gemm2_kernel<<<g2, 256, 0, stream>>>(t1_bf, w2_bf, se_b2, xf, ys); }
    ln_kernel<<<BM2 / LN_ROWS, 256, 0, stream>>>(ys, ln_g, ln_b, ln_f, ln_bf);
    sgw_kernel<<<G2 / 256, 256, 0, stream>>>(ln_f, W_hh, b_ih, b_hh, sg, gaddP);

    dim3 ggrid(BQ / BMT, G2 / BNT);   // (32, 8)
    lstm_gemm0_kernel<<<ggrid, 256, 0, stream>>>(ln_bf, wih_bf, bsumP, ln_f,
                                                 P0f, Cf, h_bfA);
    lstm_step_kernel<<<ggrid, 256, 0, stream>>>(h_bfA, whh_bf, P0f, gaddP, ln_f,
                                                Cf, h_bfB, h_f, 0);
    lstm_step_kernel<<<ggrid, 256, 0, stream>>>(h_bfB, whh_bf, P0f, gaddP, ln_f,
                                                Cf, h_bfA, h_f, 0);
    lstm_step_kernel<<<ggrid, 256, 0, stream>>>(h_bfA, whh_bf, P0f, gaddP, ln_f,
                                                Cf, h_bfB, h_f, 1);
    final_kernel<<<BQ / 4, 256, 0, stream>>>(h_f, sg, out);
}